// Round 18
// baseline (89.605 us; speedup 1.0000x reference)
//
#include <hip/hip_runtime.h>
#include <hip/hip_bf16.h>
#include <cstdint>
#include <math.h>

#define S_LEN 2048
#define D_DIM 512
#define NROWS 8192           // B*S
#define NQKV  1536           // 3*512 output cols of the fused projection
#define QK_SCALE 0.04419417382415922f   // 1/sqrt(512)

typedef unsigned short u16;
typedef unsigned long long u64;
typedef __attribute__((ext_vector_type(8))) short short8;
typedef __attribute__((ext_vector_type(4))) float floatx4;

__device__ inline floatx4 mfma16(short8 a, short8 b, floatx4 c){
  return __builtin_amdgcn_mfma_f32_16x16x32_bf16(a, b, c, 0, 0, 0);
}
__device__ inline u16 f2b(float f){
  uint32_t u = __float_as_uint(f);
  u = (u + 0x7fffu + ((u >> 16) & 1u)) >> 16;
  return (u16)u;
}
__device__ inline float b2f(u16 u){ return __uint_as_float(((uint32_t)u) << 16); }
#define GLD16(g, l) __builtin_amdgcn_global_load_lds( \
    (const __attribute__((address_space(1))) void*)(g), \
    (__attribute__((address_space(3))) void*)(l), 16, 0, 0)

// ---------------------------------------------------------------- convert (weights only)
__global__ void cvt_kernel(const float* __restrict__ Wq,
                           const float* __restrict__ Wk,
                           const float* __restrict__ Wv,
                           u16* __restrict__ wb)
{
  const int NT4 = (NQKV * D_DIM) / 4;
  for (int i = blockIdx.x * blockDim.x + threadIdx.x; i < NT4;
       i += gridDim.x * blockDim.x) {
    int e = i * 4;
    const float* src;
    if (e < 512 * 512)           src = Wq + e;
    else if (e < 2 * 512 * 512)  src = Wk + (e - 512 * 512);
    else                         src = Wv + (e - 2 * 512 * 512);
    float4 v = *(const float4*)src;
    ushort4 o;
    o.x = f2b(v.x); o.y = f2b(v.y); o.z = f2b(v.z); o.w = f2b(v.w);
    *(ushort4*)(wb + e) = o;
  }
}

// ---------------------------------------------------------------- QKV GEMM
// R15 dbuf + swizzle, with A staged from x (f32) via T14 issue-early /
// write-late reg conversion: f32 loads for kt+1 issued before the MFMA
// section, cvt+ds_write after it. Saves the x bf16 round-trip + most of cvt.
// B (weights) keeps global_load_lds from bf16 wb.
__launch_bounds__(256)
__global__ void qkv_gemm(const float* __restrict__ x,
                         const u16* __restrict__ wb,
                         const float* __restrict__ bq,
                         const float* __restrict__ bk,
                         const float* __restrict__ bv,
                         u16* __restrict__ qb,
                         u16* __restrict__ kb,
                         u16* __restrict__ vt)
{
  __shared__ alignas(16) u16 sm[2][16384];   // [buf][ A 128x64 | B 128x64 ]
  const int tid = threadIdx.x;
  const int l = tid & 63, w = tid >> 6;
  const int lr = l & 15, lg = l >> 4;
  const int wr = w >> 1, wc = w & 1;
  const int kx = (lr & 7) << 4;                                // read swizzle
  const int csw = ((tid & 7) * 16) ^ (((tid >> 3) & 7) << 4);  // source swizzle
  const int bid = blockIdx.x;
  const int xcd = bid & 7;
  const int t = bid >> 3;              // 0..95
  const int bn = t % 12, bmhi = t / 12;
  const int bm = (bmhi << 3) | xcd;    // A-panel pinned to XCD bm&7
  const int m0 = bm * 128, n0 = bn * 128;

  const float* gAf = x + (size_t)(m0 + (tid >> 3)) * D_DIM + (csw >> 1);
  const u16* gB = wb + (size_t)(n0 + (tid >> 3)) * D_DIM + (csw >> 1);

  float4 va0[4], va1[4];

#define LOADA(KT) { \
  const float* pa = gAf + (KT) * 64; \
  _Pragma("unroll") for (int jj = 0; jj < 4; jj++) { \
    va0[jj] = *(const float4*)(pa + (size_t)jj * 32 * D_DIM); \
    va1[jj] = *(const float4*)(pa + (size_t)jj * 32 * D_DIM + 4); } }

#define WRITEA(BUF) { \
  char* la = (char*)&sm[BUF][0] + tid * 16; \
  _Pragma("unroll") for (int jj = 0; jj < 4; jj++) { \
    short8 h; \
    h[0] = (short)f2b(va0[jj].x); h[1] = (short)f2b(va0[jj].y); \
    h[2] = (short)f2b(va0[jj].z); h[3] = (short)f2b(va0[jj].w); \
    h[4] = (short)f2b(va1[jj].x); h[5] = (short)f2b(va1[jj].y); \
    h[6] = (short)f2b(va1[jj].z); h[7] = (short)f2b(va1[jj].w); \
    *(short8*)(la + jj * 4096) = h; } }

#define STAGEB(BUF, KT) { \
  char* lb = (char*)&sm[BUF][8192] + tid * 16; \
  const u16* gb = gB + (KT) * 64; \
  _Pragma("unroll") for (int jj = 0; jj < 4; jj++) \
    GLD16(gb + (size_t)jj * 32 * D_DIM, lb + jj * 4096); }

  floatx4 acc[4][4];
#pragma unroll
  for (int m = 0; m < 4; m++)
#pragma unroll
    for (int n = 0; n < 4; n++) acc[m][n] = 0.0f;

  LOADA(0)
  WRITEA(0)
  STAGEB(0, 0)
  __syncthreads();

  for (int kt = 0; kt < 8; ++kt) {
    const int cb = kt & 1;
    if (kt < 7) {
      LOADA(kt + 1)          // issue f32 loads early: hide under MFMA
      STAGEB(cb ^ 1, kt + 1)
    }
#pragma unroll
    for (int kk = 0; kk < 2; ++kk) {
      short8 a[4], bfr[4];
#pragma unroll
      for (int m = 0; m < 4; m++)
        a[m] = *(const short8*)((const char*)&sm[cb][0]
                + (wr * 64 + m * 16 + lr) * 128 + ((kk * 64 + lg * 16) ^ kx));
#pragma unroll
      for (int n = 0; n < 4; n++)
        bfr[n] = *(const short8*)((const char*)&sm[cb][0] + 16384
                + (wc * 64 + n * 16 + lr) * 128 + ((kk * 64 + lg * 16) ^ kx));
#pragma unroll
      for (int m = 0; m < 4; m++)
#pragma unroll
        for (int n = 0; n < 4; n++)
          acc[m][n] = mfma16(a[m], bfr[n], acc[m][n]);
    }
    if (kt < 7) WRITEA(cb ^ 1)   // write late: after compute, before barrier
    __syncthreads();
  }
#undef LOADA
#undef WRITEA
#undef STAGEB

  if (n0 < 1024) {
    const float* bias = (n0 < 512) ? bq : bk;
    u16* dst = (n0 < 512) ? qb : kb;
    const float scl = (n0 < 512) ? QK_SCALE : 1.0f;
    const int nbase = n0 & 511;
#pragma unroll
    for (int n = 0; n < 4; n++) {
      int gn = nbase + wc * 64 + n * 16 + lr;
      float bia = bias[gn];
#pragma unroll
      for (int m = 0; m < 4; m++) {
        int gm0 = m0 + wr * 64 + m * 16 + lg * 4;
#pragma unroll
        for (int r = 0; r < 4; r++)
          dst[(size_t)(gm0 + r) * D_DIM + gn] = f2b((acc[m][n][r] + bia) * scl);
      }
    }
  } else {
    const int nbase = n0 - 1024;
    const int bIdx = m0 >> 11;
    const int s0 = m0 & 2047;
    __syncthreads();
#pragma unroll
    for (int h = 0; h < 2; ++h) {
      if (wc == h) {
#pragma unroll
        for (int n = 0; n < 4; n++) {
          int lrow = n * 16 + lr;
          float bia = bv[nbase + h * 64 + lrow];
#pragma unroll
          for (int m = 0; m < 4; m++) {
            int lcol = wr * 64 + m * 16 + lg * 4;
#pragma unroll
            for (int r = 0; r < 4; r++)
              sm[0][lrow * 136 + lcol + r] = f2b(acc[m][n][r] + bia);
          }
        }
      }
      __syncthreads();
      {
        int row = tid >> 2;
        int c0 = (tid & 3) * 32;
        u16* dstp = vt + (size_t)bIdx * D_DIM * S_LEN
                       + (size_t)(nbase + h * 64 + row) * S_LEN + s0 + c0;
        const u16* srcp = &sm[0][row * 136 + c0];
#pragma unroll
        for (int jj = 0; jj < 4; jj++)
          *(short8*)(dstp + jj * 8) = *(const short8*)(srcp + jj * 8);
      }
      __syncthreads();
    }
  }
}

// ---------------------------------------------------------------- S = exp(K.Q^T) GEMM
// R15 double-buffered structure + swizzled LDS tiles. Unchanged.
__launch_bounds__(256)
__global__ void s_gemm(const u16* __restrict__ qb,
                       const u16* __restrict__ kb,
                       u16* __restrict__ P,
                       float* __restrict__ pRS)
{
  __shared__ alignas(16) u16 sm[2][16384];
  const int tid = threadIdx.x;
  const int l = tid & 63, w = tid >> 6;
  const int lr = l & 15, lg = l >> 4;
  const int wr = w >> 1, wc = w & 1;
  const int kx = (lr & 7) << 4;
  const int csw = ((tid & 7) * 16) ^ (((tid >> 3) & 7) << 4);
  const int bid = blockIdx.x;
  const int xcd = bid & 7;
  const int b = xcd >> 1;
  const int j = (bid >> 3) * 2 + (xcd & 1);   // 0..135
  float g = sqrtf(8.f * (float)j + 1.f);
  int qt = (int)((g - 1.f) * 0.5f + 1e-4f);
  while ((qt + 1) * (qt + 2) / 2 <= j) ++qt;
  while (qt * (qt + 1) / 2 > j) --qt;
  const int kt = j - qt * (qt + 1) / 2;

  const u16* gA = kb + ((size_t)(b * S_LEN + kt * 128 + (tid >> 3))) * D_DIM + (csw >> 1);
  const u16* gB = qb + ((size_t)(b * S_LEN + qt * 128 + (tid >> 3))) * D_DIM + (csw >> 1);

#define STAGES(BUF, KT) { \
  char* la = (char*)&sm[BUF][0] + tid * 16; \
  char* lb = (char*)&sm[BUF][8192] + tid * 16; \
  const u16* ga = gA + (KT) * 64; \
  const u16* gb = gB + (KT) * 64; \
  _Pragma("unroll") for (int jj = 0; jj < 4; jj++) { \
    GLD16(ga + (size_t)jj * 32 * D_DIM, la + jj * 4096); \
    GLD16(gb + (size_t)jj * 32 * D_DIM, lb + jj * 4096); } }

  floatx4 acc[4][4];
#pragma unroll
  for (int m = 0; m < 4; m++)
#pragma unroll
    for (int n = 0; n < 4; n++) acc[m][n] = 0.0f;

  STAGES(0, 0)
  __syncthreads();
  for (int ks = 0; ks < 8; ++ks) {
    const int cb = ks & 1;
    if (ks < 7) STAGES(cb ^ 1, ks + 1)
#pragma unroll
    for (int kk = 0; kk < 2; ++kk) {
      short8 a[4], bfr[4];
#pragma unroll
      for (int m = 0; m < 4; m++)
        a[m] = *(const short8*)((const char*)&sm[cb][0]
                + (wr * 64 + m * 16 + lr) * 128 + ((kk * 64 + lg * 16) ^ kx));
#pragma unroll
      for (int n = 0; n < 4; n++)
        bfr[n] = *(const short8*)((const char*)&sm[cb][0] + 16384
                + (wc * 64 + n * 16 + lr) * 128 + ((kk * 64 + lg * 16) ^ kx));
#pragma unroll
      for (int m = 0; m < 4; m++)
#pragma unroll
        for (int n = 0; n < 4; n++)
          acc[m][n] = mfma16(a[m], bfr[n], acc[m][n]);
    }
    __syncthreads();
  }
#undef STAGES

  // epilogue: exp + mask, u64-packed P stores, rowsum partials
  const bool diag = (kt == qt);
  u16* Pb = P + (size_t)b * S_LEN * S_LEN;
#pragma unroll
  for (int n = 0; n < 4; ++n) {
    const int q = qt * 128 + wc * 64 + n * 16 + lr;
    float rs = 0.f;
#pragma unroll
    for (int m = 0; m < 4; ++m) {
      const int kb0 = kt * 128 + wr * 64 + m * 16 + lg * 4;
      u16 h[4];
#pragma unroll
      for (int r = 0; r < 4; ++r) {
        float e = __expf(acc[m][n][r]);
        if (diag && (kb0 + r > q)) e = 0.f;
        h[r] = f2b(e);
        rs += b2f(h[r]);
      }
      u64 pk = (u64)h[0] | ((u64)h[1] << 16) | ((u64)h[2] << 32) | ((u64)h[3] << 48);
      *(u64*)(Pb + (size_t)q * S_LEN + kb0) = pk;
    }
    rs += __shfl_xor(rs, 16);
    rs += __shfl_xor(rs, 32);
    if (lg == 0)
      pRS[(size_t)(b * S_LEN + q) * 32 + kt * 2 + wr] = rs;
  }
}

// ---------------------------------------------------------------- O = (P.V)/rsum
// R15 m97-dbuf structure (BK=64, grid 512, longest-first) + swizzled LDS.
__launch_bounds__(256)
__global__ void pv_gemm(const u16* __restrict__ P,
                       const float* __restrict__ pRS,
                       const u16* __restrict__ vt,
                       float* __restrict__ out)
{
  __shared__ alignas(16) u16 sm[2][12288];   // A 128x64 @0 | B 64x64 @byte 16384
  __shared__ float rinv[64];

  const int tid = threadIdx.x;
  const int l = tid & 63, w = tid >> 6;
  const int lr = l & 15, lg = l >> 4;
  const int wr = w >> 1, wc = w & 1;         // wave: 64d x 32q quadrant
  const int kx = (lr & 7) << 4;
  const int csw = ((tid & 7) * 16) ^ (((tid >> 3) & 7) << 4);
  const int bid = blockIdx.x;
  const int xcd = bid & 7;
  const int b = xcd >> 1, xl = xcd & 1;
  const int t = bid >> 3;                    // 0..63
  const int m = t & 3;                       // d-tile (128)
  const int qraw = ((t >> 2) << 1) | xl;     // 0..31
  const int qt = 31 - qraw;                  // longest first
  const int m0 = m * 128;
  const int q0 = qt * 64;
  const int nks = qt + 1;                    // BK=64 k-steps

  const u16* gA = vt + (size_t)b * D_DIM * S_LEN
                     + (size_t)(m0 + (tid >> 3)) * S_LEN + (csw >> 1);
  const u16* gB = P + (size_t)b * S_LEN * S_LEN
                    + (size_t)(q0 + (tid >> 3)) * S_LEN + (csw >> 1);

  // rsum prologue
  {
    const int qi = tid >> 2;                 // 0..63
    const int qrow = q0 + qi;
    const int ns = ((qrow >> 7) + 1) * 2;
    float s = 0.f;
    for (int ss = tid & 3; ss < ns; ss += 4)
      s += pRS[(size_t)(b * S_LEN + qrow) * 32 + ss];
    s += __shfl_xor(s, 1);
    s += __shfl_xor(s, 2);
    if ((tid & 3) == 0) rinv[qi] = 1.0f / s;
  }

#define STAGEPV(BUF, KS) { \
  char* la = (char*)&sm[BUF][0] + tid * 16; \
  char* lb = (char*)&sm[BUF][8192] + tid * 16; \
  const u16* ga = gA + (KS) * 64; \
  const u16* gb = gB + (KS) * 64; \
  _Pragma("unroll") for (int jj = 0; jj < 4; jj++) \
    GLD16(ga + (size_t)jj * 32 * S_LEN, la + jj * 4096); \
  _Pragma("unroll") for (int jj = 0; jj < 2; jj++) \
    GLD16(gb + (size_t)jj * 32 * S_LEN, lb + jj * 4096); }

  floatx4 acc[4][2];
#pragma unroll
  for (int mm = 0; mm < 4; mm++) { acc[mm][0] = 0.0f; acc[mm][1] = 0.0f; }

  STAGEPV(0, 0)
  __syncthreads();
  for (int ks = 0; ks < nks; ++ks) {
    const int cb = ks & 1;
    if (ks < nks - 1) STAGEPV(cb ^ 1, ks + 1)
#pragma unroll
    for (int kk = 0; kk < 2; ++kk) {
      short8 a[4], bfr[2];
#pragma unroll
      for (int mm = 0; mm < 4; mm++)
        a[mm] = *(const short8*)((const char*)&sm[cb][0]
                + (wr * 64 + mm * 16 + lr) * 128 + ((kk * 64 + lg * 16) ^ kx));
#pragma unroll
      for (int n = 0; n < 2; n++)
        bfr[n] = *(const short8*)((const char*)&sm[cb][0] + 16384
                + (wc * 32 + n * 16 + lr) * 128 + ((kk * 64 + lg * 16) ^ kx));
#pragma unroll
      for (int mm = 0; mm < 4; mm++)
#pragma unroll
        for (int n = 0; n < 2; n++)
          acc[mm][n] = mfma16(a[mm], bfr[n], acc[mm][n]);
    }
    __syncthreads();
  }
#undef STAGEPV

  // epilogue: normalize + float4 stores. d = m0+wr*64+mm*16+lg*4+r (C row),
  // q = wc*32+n*16+lr (C col).
#pragma unroll
  for (int n = 0; n < 2; ++n) {
    const int q = q0 + wc * 32 + n * 16 + lr;
    const float inv = rinv[wc * 32 + n * 16 + lr];
    float* op = out + (size_t)(b * S_LEN + q) * D_DIM + m0 + wr * 64 + lg * 4;
#pragma unroll
    for (int mm = 0; mm < 4; ++mm) {
      float4 v;
      v.x = acc[mm][n][0] * inv;
      v.y = acc[mm][n][1] * inv;
      v.z = acc[mm][n][2] * inv;
      v.w = acc[mm][n][3] * inv;
      *(float4*)(op + mm * 16) = v;
    }
  }
}

// ---------------------------------------------------------------- launch
extern "C" void kernel_launch(void* const* d_in, const int* in_sizes, int n_in,
                              void* d_out, int out_size, void* d_ws, size_t ws_size,
                              hipStream_t stream)
{
  const float* x  = (const float*)d_in[0];
  const float* Wq = (const float*)d_in[1];
  const float* bq = (const float*)d_in[2];
  const float* Wk = (const float*)d_in[3];
  const float* bk = (const float*)d_in[4];
  const float* Wv = (const float*)d_in[5];
  const float* bv = (const float*)d_in[6];
  float* out = (float*)d_out;

  u16* xw = (u16*)d_ws;
  u16* wb = xw;                              // [1536][512] bf16 (weights)
  u16* qb = wb + (size_t)NQKV * D_DIM;       // [8192][512] bf16 (scaled)
  u16* kb = qb + (size_t)NROWS * D_DIM;      // [8192][512] bf16
  u16* vt = kb + (size_t)NROWS * D_DIM;      // [4][512][2048] bf16 (V^T)
  u16* P  = vt + (size_t)NROWS * D_DIM;      // [4][2048][2048] bf16 (exp scores)
  float* pRS = (float*)(P + (size_t)4 * S_LEN * S_LEN);  // [8192][32] f32 rowsum partials

  hipLaunchKernelGGL(cvt_kernel, dim3(512), dim3(256), 0, stream, Wq, Wk, Wv, wb);
  hipLaunchKernelGGL(qkv_gemm, dim3(768), dim3(256), 0, stream,
                     x, wb, bq, bk, bv, qb, kb, vt);
  hipLaunchKernelGGL(s_gemm, dim3(544), dim3(256), 0, stream, qb, kb, P, pRS);
  hipLaunchKernelGGL(pv_gemm, dim3(512), dim3(256), 0, stream, P, pRS, vt, out);
}

// Round 19
// 78.893 us; speedup vs baseline: 1.1358x; 1.1358x over previous
//
#include <hip/hip_runtime.h>
#include <hip/hip_bf16.h>
#include <cstdint>
#include <math.h>

#define S_LEN 2048
#define D_DIM 512
#define NROWS 8192           // B*S
#define NQKV  1536           // 3*512 output cols of the fused projection
#define QK_SCALE 0.04419417382415922f   // 1/sqrt(512)

typedef unsigned short u16;
typedef unsigned long long u64;
typedef __attribute__((ext_vector_type(8))) short short8;
typedef __attribute__((ext_vector_type(4))) float floatx4;

__device__ inline floatx4 mfma16(short8 a, short8 b, floatx4 c){
  return __builtin_amdgcn_mfma_f32_16x16x32_bf16(a, b, c, 0, 0, 0);
}
__device__ inline u16 f2b(float f){
  uint32_t u = __float_as_uint(f);
  u = (u + 0x7fffu + ((u >> 16) & 1u)) >> 16;
  return (u16)u;
}
__device__ inline float b2f(u16 u){ return __uint_as_float(((uint32_t)u) << 16); }
#define GLD16(g, l) __builtin_amdgcn_global_load_lds( \
    (const __attribute__((address_space(1))) void*)(g), \
    (__attribute__((address_space(3))) void*)(l), 16, 0, 0)

// ---------------------------------------------------------------- convert
__global__ void cvt_kernel(const float* __restrict__ x,
                           const float* __restrict__ Wq,
                           const float* __restrict__ Wk,
                           const float* __restrict__ Wv,
                           u16* __restrict__ xw)
{
  const int NT4 = (NROWS * D_DIM) / 4 + (NQKV * D_DIM) / 4;
  for (int i = blockIdx.x * blockDim.x + threadIdx.x; i < NT4;
       i += gridDim.x * blockDim.x) {
    int e = i * 4;
    const float* src;
    if (e < NROWS * D_DIM) {
      src = x + e;
    } else {
      int j = e - NROWS * D_DIM;
      if (j < 512 * 512)           src = Wq + j;
      else if (j < 2 * 512 * 512)  src = Wk + (j - 512 * 512);
      else                         src = Wv + (j - 2 * 512 * 512);
    }
    float4 v = *(const float4*)src;
    ushort4 o;
    o.x = f2b(v.x); o.y = f2b(v.y); o.z = f2b(v.z); o.w = f2b(v.w);
    *(ushort4*)(xw + e) = o;
  }
}

// ---------------------------------------------------------------- QKV GEMM
// Session optimum (R15/R17, 78.9-79.6 us): double-buffered GLD16 staging +
// both-sides XOR swizzle. R18 proved reg-staged A (fused f32 cvt) loses ~23us
// (m151 confirmed in-session: reg-staging < global_load_lds at this tile).
__launch_bounds__(256)
__global__ void qkv_gemm(const u16* __restrict__ xb,
                         const u16* __restrict__ wb,
                         const float* __restrict__ bq,
                         const float* __restrict__ bk,
                         const float* __restrict__ bv,
                         u16* __restrict__ qb,
                         u16* __restrict__ kb,
                         u16* __restrict__ vt)
{
  __shared__ alignas(16) u16 sm[2][16384];   // [buf][ A 128x64 | B 128x64 ]
  const int tid = threadIdx.x;
  const int l = tid & 63, w = tid >> 6;
  const int lr = l & 15, lg = l >> 4;
  const int wr = w >> 1, wc = w & 1;
  const int kx = (lr & 7) << 4;                                // read swizzle
  const int csw = ((tid & 7) * 16) ^ (((tid >> 3) & 7) << 4);  // source swizzle
  const int bid = blockIdx.x;
  const int xcd = bid & 7;
  const int t = bid >> 3;              // 0..95
  const int bn = t % 12, bmhi = t / 12;
  const int bm = (bmhi << 3) | xcd;    // A-panel pinned to XCD bm&7
  const int m0 = bm * 128, n0 = bn * 128;

  const u16* gA = xb + (size_t)(m0 + (tid >> 3)) * D_DIM + (csw >> 1);
  const u16* gB = wb + (size_t)(n0 + (tid >> 3)) * D_DIM + (csw >> 1);

#define STAGEK(BUF, KT) { \
  char* la = (char*)&sm[BUF][0] + tid * 16; \
  char* lb = (char*)&sm[BUF][8192] + tid * 16; \
  const u16* ga = gA + (KT) * 64; \
  const u16* gb = gB + (KT) * 64; \
  _Pragma("unroll") for (int jj = 0; jj < 4; jj++) { \
    GLD16(ga + (size_t)jj * 32 * D_DIM, la + jj * 4096); \
    GLD16(gb + (size_t)jj * 32 * D_DIM, lb + jj * 4096); } }

  floatx4 acc[4][4];
#pragma unroll
  for (int m = 0; m < 4; m++)
#pragma unroll
    for (int n = 0; n < 4; n++) acc[m][n] = 0.0f;

  STAGEK(0, 0)
  __syncthreads();

  for (int kt = 0; kt < 8; ++kt) {
    const int cb = kt & 1;
    if (kt < 7) STAGEK(cb ^ 1, kt + 1)
#pragma unroll
    for (int kk = 0; kk < 2; ++kk) {
      short8 a[4], bfr[4];
#pragma unroll
      for (int m = 0; m < 4; m++)
        a[m] = *(const short8*)((const char*)&sm[cb][0]
                + (wr * 64 + m * 16 + lr) * 128 + ((kk * 64 + lg * 16) ^ kx));
#pragma unroll
      for (int n = 0; n < 4; n++)
        bfr[n] = *(const short8*)((const char*)&sm[cb][0] + 16384
                + (wc * 64 + n * 16 + lr) * 128 + ((kk * 64 + lg * 16) ^ kx));
#pragma unroll
      for (int m = 0; m < 4; m++)
#pragma unroll
        for (int n = 0; n < 4; n++)
          acc[m][n] = mfma16(a[m], bfr[n], acc[m][n]);
    }
    __syncthreads();
  }
#undef STAGEK

  if (n0 < 1024) {
    const float* bias = (n0 < 512) ? bq : bk;
    u16* dst = (n0 < 512) ? qb : kb;
    const float scl = (n0 < 512) ? QK_SCALE : 1.0f;
    const int nbase = n0 & 511;
#pragma unroll
    for (int n = 0; n < 4; n++) {
      int gn = nbase + wc * 64 + n * 16 + lr;
      float bia = bias[gn];
#pragma unroll
      for (int m = 0; m < 4; m++) {
        int gm0 = m0 + wr * 64 + m * 16 + lg * 4;
#pragma unroll
        for (int r = 0; r < 4; r++)
          dst[(size_t)(gm0 + r) * D_DIM + gn] = f2b((acc[m][n][r] + bia) * scl);
      }
    }
  } else {
    const int nbase = n0 - 1024;
    const int bIdx = m0 >> 11;
    const int s0 = m0 & 2047;
    __syncthreads();
#pragma unroll
    for (int h = 0; h < 2; ++h) {
      if (wc == h) {
#pragma unroll
        for (int n = 0; n < 4; n++) {
          int lrow = n * 16 + lr;
          float bia = bv[nbase + h * 64 + lrow];
#pragma unroll
          for (int m = 0; m < 4; m++) {
            int lcol = wr * 64 + m * 16 + lg * 4;
#pragma unroll
            for (int r = 0; r < 4; r++)
              sm[0][lrow * 136 + lcol + r] = f2b(acc[m][n][r] + bia);
          }
        }
      }
      __syncthreads();
      {
        int row = tid >> 2;
        int c0 = (tid & 3) * 32;
        u16* dstp = vt + (size_t)bIdx * D_DIM * S_LEN
                       + (size_t)(nbase + h * 64 + row) * S_LEN + s0 + c0;
        const u16* srcp = &sm[0][row * 136 + c0];
#pragma unroll
        for (int jj = 0; jj < 4; jj++)
          *(short8*)(dstp + jj * 8) = *(const short8*)(srcp + jj * 8);
      }
      __syncthreads();
    }
  }
}

// ---------------------------------------------------------------- S = exp(K.Q^T) GEMM
__launch_bounds__(256)
__global__ void s_gemm(const u16* __restrict__ qb,
                       const u16* __restrict__ kb,
                       u16* __restrict__ P,
                       float* __restrict__ pRS)
{
  __shared__ alignas(16) u16 sm[2][16384];
  const int tid = threadIdx.x;
  const int l = tid & 63, w = tid >> 6;
  const int lr = l & 15, lg = l >> 4;
  const int wr = w >> 1, wc = w & 1;
  const int kx = (lr & 7) << 4;
  const int csw = ((tid & 7) * 16) ^ (((tid >> 3) & 7) << 4);
  const int bid = blockIdx.x;
  const int xcd = bid & 7;
  const int b = xcd >> 1;
  const int j = (bid >> 3) * 2 + (xcd & 1);   // 0..135
  float g = sqrtf(8.f * (float)j + 1.f);
  int qt = (int)((g - 1.f) * 0.5f + 1e-4f);
  while ((qt + 1) * (qt + 2) / 2 <= j) ++qt;
  while (qt * (qt + 1) / 2 > j) --qt;
  const int kt = j - qt * (qt + 1) / 2;

  const u16* gA = kb + ((size_t)(b * S_LEN + kt * 128 + (tid >> 3))) * D_DIM + (csw >> 1);
  const u16* gB = qb + ((size_t)(b * S_LEN + qt * 128 + (tid >> 3))) * D_DIM + (csw >> 1);

#define STAGES(BUF, KT) { \
  char* la = (char*)&sm[BUF][0] + tid * 16; \
  char* lb = (char*)&sm[BUF][8192] + tid * 16; \
  const u16* ga = gA + (KT) * 64; \
  const u16* gb = gB + (KT) * 64; \
  _Pragma("unroll") for (int jj = 0; jj < 4; jj++) { \
    GLD16(ga + (size_t)jj * 32 * D_DIM, la + jj * 4096); \
    GLD16(gb + (size_t)jj * 32 * D_DIM, lb + jj * 4096); } }

  floatx4 acc[4][4];
#pragma unroll
  for (int m = 0; m < 4; m++)
#pragma unroll
    for (int n = 0; n < 4; n++) acc[m][n] = 0.0f;

  STAGES(0, 0)
  __syncthreads();
  for (int ks = 0; ks < 8; ++ks) {
    const int cb = ks & 1;
    if (ks < 7) STAGES(cb ^ 1, ks + 1)
#pragma unroll
    for (int kk = 0; kk < 2; ++kk) {
      short8 a[4], bfr[4];
#pragma unroll
      for (int m = 0; m < 4; m++)
        a[m] = *(const short8*)((const char*)&sm[cb][0]
                + (wr * 64 + m * 16 + lr) * 128 + ((kk * 64 + lg * 16) ^ kx));
#pragma unroll
      for (int n = 0; n < 4; n++)
        bfr[n] = *(const short8*)((const char*)&sm[cb][0] + 16384
                + (wc * 64 + n * 16 + lr) * 128 + ((kk * 64 + lg * 16) ^ kx));
#pragma unroll
      for (int m = 0; m < 4; m++)
#pragma unroll
        for (int n = 0; n < 4; n++)
          acc[m][n] = mfma16(a[m], bfr[n], acc[m][n]);
    }
    __syncthreads();
  }
#undef STAGES

  // epilogue: exp + mask, u64-packed P stores, rowsum partials
  const bool diag = (kt == qt);
  u16* Pb = P + (size_t)b * S_LEN * S_LEN;
#pragma unroll
  for (int n = 0; n < 4; ++n) {
    const int q = qt * 128 + wc * 64 + n * 16 + lr;
    float rs = 0.f;
#pragma unroll
    for (int m = 0; m < 4; ++m) {
      const int kb0 = kt * 128 + wr * 64 + m * 16 + lg * 4;
      u16 h[4];
#pragma unroll
      for (int r = 0; r < 4; ++r) {
        float e = __expf(acc[m][n][r]);
        if (diag && (kb0 + r > q)) e = 0.f;
        h[r] = f2b(e);
        rs += b2f(h[r]);
      }
      u64 pk = (u64)h[0] | ((u64)h[1] << 16) | ((u64)h[2] << 32) | ((u64)h[3] << 48);
      *(u64*)(Pb + (size_t)q * S_LEN + kb0) = pk;
    }
    rs += __shfl_xor(rs, 16);
    rs += __shfl_xor(rs, 32);
    if (lg == 0)
      pRS[(size_t)(b * S_LEN + q) * 32 + kt * 2 + wr] = rs;
  }
}

// ---------------------------------------------------------------- O = (P.V)/rsum
__launch_bounds__(256)
__global__ void pv_gemm(const u16* __restrict__ P,
                       const float* __restrict__ pRS,
                       const u16* __restrict__ vt,
                       float* __restrict__ out)
{
  __shared__ alignas(16) u16 sm[2][12288];   // A 128x64 @0 | B 64x64 @byte 16384
  __shared__ float rinv[64];

  const int tid = threadIdx.x;
  const int l = tid & 63, w = tid >> 6;
  const int lr = l & 15, lg = l >> 4;
  const int wr = w >> 1, wc = w & 1;         // wave: 64d x 32q quadrant
  const int kx = (lr & 7) << 4;
  const int csw = ((tid & 7) * 16) ^ (((tid >> 3) & 7) << 4);
  const int bid = blockIdx.x;
  const int xcd = bid & 7;
  const int b = xcd >> 1, xl = xcd & 1;
  const int t = bid >> 3;                    // 0..63
  const int m = t & 3;                       // d-tile (128)
  const int qraw = ((t >> 2) << 1) | xl;     // 0..31
  const int qt = 31 - qraw;                  // longest first
  const int m0 = m * 128;
  const int q0 = qt * 64;
  const int nks = qt + 1;                    // BK=64 k-steps

  const u16* gA = vt + (size_t)b * D_DIM * S_LEN
                     + (size_t)(m0 + (tid >> 3)) * S_LEN + (csw >> 1);
  const u16* gB = P + (size_t)b * S_LEN * S_LEN
                    + (size_t)(q0 + (tid >> 3)) * S_LEN + (csw >> 1);

  // rsum prologue
  {
    const int qi = tid >> 2;                 // 0..63
    const int qrow = q0 + qi;
    const int ns = ((qrow >> 7) + 1) * 2;
    float s = 0.f;
    for (int ss = tid & 3; ss < ns; ss += 4)
      s += pRS[(size_t)(b * S_LEN + qrow) * 32 + ss];
    s += __shfl_xor(s, 1);
    s += __shfl_xor(s, 2);
    if ((tid & 3) == 0) rinv[qi] = 1.0f / s;
  }

#define STAGEPV(BUF, KS) { \
  char* la = (char*)&sm[BUF][0] + tid * 16; \
  char* lb = (char*)&sm[BUF][8192] + tid * 16; \
  const u16* ga = gA + (KS) * 64; \
  const u16* gb = gB + (KS) * 64; \
  _Pragma("unroll") for (int jj = 0; jj < 4; jj++) \
    GLD16(ga + (size_t)jj * 32 * S_LEN, la + jj * 4096); \
  _Pragma("unroll") for (int jj = 0; jj < 2; jj++) \
    GLD16(gb + (size_t)jj * 32 * S_LEN, lb + jj * 4096); }

  floatx4 acc[4][2];
#pragma unroll
  for (int mm = 0; mm < 4; mm++) { acc[mm][0] = 0.0f; acc[mm][1] = 0.0f; }

  STAGEPV(0, 0)
  __syncthreads();
  for (int ks = 0; ks < nks; ++ks) {
    const int cb = ks & 1;
    if (ks < nks - 1) STAGEPV(cb ^ 1, ks + 1)
#pragma unroll
    for (int kk = 0; kk < 2; ++kk) {
      short8 a[4], bfr[2];
#pragma unroll
      for (int mm = 0; mm < 4; mm++)
        a[mm] = *(const short8*)((const char*)&sm[cb][0]
                + (wr * 64 + mm * 16 + lr) * 128 + ((kk * 64 + lg * 16) ^ kx));
#pragma unroll
      for (int n = 0; n < 2; n++)
        bfr[n] = *(const short8*)((const char*)&sm[cb][0] + 16384
                + (wc * 32 + n * 16 + lr) * 128 + ((kk * 64 + lg * 16) ^ kx));
#pragma unroll
      for (int mm = 0; mm < 4; mm++)
#pragma unroll
        for (int n = 0; n < 2; n++)
          acc[mm][n] = mfma16(a[mm], bfr[n], acc[mm][n]);
    }
    __syncthreads();
  }
#undef STAGEPV

  // epilogue: normalize + float4 stores. d = m0+wr*64+mm*16+lg*4+r (C row),
  // q = wc*32+n*16+lr (C col).
#pragma unroll
  for (int n = 0; n < 2; ++n) {
    const int q = q0 + wc * 32 + n * 16 + lr;
    const float inv = rinv[wc * 32 + n * 16 + lr];
    float* op = out + (size_t)(b * S_LEN + q) * D_DIM + m0 + wr * 64 + lg * 4;
#pragma unroll
    for (int mm = 0; mm < 4; ++mm) {
      float4 v;
      v.x = acc[mm][n][0] * inv;
      v.y = acc[mm][n][1] * inv;
      v.z = acc[mm][n][2] * inv;
      v.w = acc[mm][n][3] * inv;
      *(float4*)(op + mm * 16) = v;
    }
  }
}

// ---------------------------------------------------------------- launch
extern "C" void kernel_launch(void* const* d_in, const int* in_sizes, int n_in,
                              void* d_out, int out_size, void* d_ws, size_t ws_size,
                              hipStream_t stream)
{
  const float* x  = (const float*)d_in[0];
  const float* Wq = (const float*)d_in[1];
  const float* bq = (const float*)d_in[2];
  const float* Wk = (const float*)d_in[3];
  const float* bk = (const float*)d_in[4];
  const float* Wv = (const float*)d_in[5];
  const float* bv = (const float*)d_in[6];
  float* out = (float*)d_out;

  u16* xw = (u16*)d_ws;
  u16* xb = xw;                              // [8192][512] bf16
  u16* wb = xb + (size_t)NROWS * D_DIM;      // [1536][512] bf16
  u16* qb = wb + (size_t)NQKV * D_DIM;       // [8192][512] bf16 (scaled)
  u16* kb = qb + (size_t)NROWS * D_DIM;      // [8192][512] bf16
  u16* vt = kb + (size_t)NROWS * D_DIM;      // [4][512][2048] bf16 (V^T)
  u16* P  = vt + (size_t)NROWS * D_DIM;      // [4][2048][2048] bf16 (exp scores)
  float* pRS = (float*)(P + (size_t)4 * S_LEN * S_LEN);  // [8192][32] f32 rowsum partials

  hipLaunchKernelGGL(cvt_kernel, dim3(2048), dim3(256), 0, stream, x, Wq, Wk, Wv, xw);
  hipLaunchKernelGGL(qkv_gemm, dim3(768), dim3(256), 0, stream,
                     xb, wb, bq, bk, bv, qb, kb, vt);
  hipLaunchKernelGGL(s_gemm, dim3(544), dim3(256), 0, stream, qb, kb, P, pRS);
  hipLaunchKernelGGL(pv_gemm, dim3(512), dim3(256), 0, stream, P, pRS, vt, out);
}

// Round 20
// 78.321 us; speedup vs baseline: 1.1441x; 1.0073x over previous
//
#include <hip/hip_runtime.h>
#include <hip/hip_bf16.h>
#include <cstdint>
#include <math.h>

#define S_LEN 2048
#define D_DIM 512
#define NROWS 8192           // B*S
#define NQKV  1536           // 3*512 output cols of the fused projection
#define QK_SCALE 0.04419417382415922f   // 1/sqrt(512)

typedef unsigned short u16;
typedef unsigned long long u64;
typedef __attribute__((ext_vector_type(8))) short short8;
typedef __attribute__((ext_vector_type(4))) float floatx4;

__device__ inline floatx4 mfma16(short8 a, short8 b, floatx4 c){
  return __builtin_amdgcn_mfma_f32_16x16x32_bf16(a, b, c, 0, 0, 0);
}
__device__ inline u16 f2b(float f){
  uint32_t u = __float_as_uint(f);
  u = (u + 0x7fffu + ((u >> 16) & 1u)) >> 16;
  return (u16)u;
}
__device__ inline float b2f(u16 u){ return __uint_as_float(((uint32_t)u) << 16); }
#define GLD16(g, l) __builtin_amdgcn_global_load_lds( \
    (const __attribute__((address_space(1))) void*)(g), \
    (__attribute__((address_space(3))) void*)(l), 16, 0, 0)

// ---------------------------------------------------------------- convert
__global__ void cvt_kernel(const float* __restrict__ x,
                           const float* __restrict__ Wq,
                           const float* __restrict__ Wk,
                           const float* __restrict__ Wv,
                           u16* __restrict__ xw)
{
  const int NT4 = (NROWS * D_DIM) / 4 + (NQKV * D_DIM) / 4;
  for (int i = blockIdx.x * blockDim.x + threadIdx.x; i < NT4;
       i += gridDim.x * blockDim.x) {
    int e = i * 4;
    const float* src;
    if (e < NROWS * D_DIM) {
      src = x + e;
    } else {
      int j = e - NROWS * D_DIM;
      if (j < 512 * 512)           src = Wq + j;
      else if (j < 2 * 512 * 512)  src = Wk + (j - 512 * 512);
      else                         src = Wv + (j - 2 * 512 * 512);
    }
    float4 v = *(const float4*)src;
    ushort4 o;
    o.x = f2b(v.x); o.y = f2b(v.y); o.z = f2b(v.z); o.w = f2b(v.w);
    *(ushort4*)(xw + e) = o;
  }
}

// ---------------------------------------------------------------- QKV GEMM
__launch_bounds__(256)
__global__ void qkv_gemm(const u16* __restrict__ xb,
                         const u16* __restrict__ wb,
                         const float* __restrict__ bq,
                         const float* __restrict__ bk,
                         const float* __restrict__ bv,
                         u16* __restrict__ qb,
                         u16* __restrict__ kb,
                         u16* __restrict__ vt)
{
  __shared__ alignas(16) u16 sm[2][16384];   // [buf][ A 128x64 | B 128x64 ]
  const int tid = threadIdx.x;
  const int l = tid & 63, w = tid >> 6;
  const int lr = l & 15, lg = l >> 4;
  const int wr = w >> 1, wc = w & 1;
  const int kx = (lr & 7) << 4;                                // read swizzle
  const int csw = ((tid & 7) * 16) ^ (((tid >> 3) & 7) << 4);  // source swizzle
  const int bid = blockIdx.x;
  const int xcd = bid & 7;
  const int t = bid >> 3;              // 0..95
  const int bn = t % 12, bmhi = t / 12;
  const int bm = (bmhi << 3) | xcd;    // A-panel pinned to XCD bm&7
  const int m0 = bm * 128, n0 = bn * 128;

  const u16* gA = xb + (size_t)(m0 + (tid >> 3)) * D_DIM + (csw >> 1);
  const u16* gB = wb + (size_t)(n0 + (tid >> 3)) * D_DIM + (csw >> 1);

#define STAGEK(BUF, KT) { \
  char* la = (char*)&sm[BUF][0] + tid * 16; \
  char* lb = (char*)&sm[BUF][8192] + tid * 16; \
  const u16* ga = gA + (KT) * 64; \
  const u16* gb = gB + (KT) * 64; \
  _Pragma("unroll") for (int jj = 0; jj < 4; jj++) { \
    GLD16(ga + (size_t)jj * 32 * D_DIM, la + jj * 4096); \
    GLD16(gb + (size_t)jj * 32 * D_DIM, lb + jj * 4096); } }

  floatx4 acc[4][4];
#pragma unroll
  for (int m = 0; m < 4; m++)
#pragma unroll
    for (int n = 0; n < 4; n++) acc[m][n] = 0.0f;

  STAGEK(0, 0)
  __syncthreads();

  for (int kt = 0; kt < 8; ++kt) {
    const int cb = kt & 1;
    if (kt < 7) STAGEK(cb ^ 1, kt + 1)
#pragma unroll
    for (int kk = 0; kk < 2; ++kk) {
      short8 a[4], bfr[4];
#pragma unroll
      for (int m = 0; m < 4; m++)
        a[m] = *(const short8*)((const char*)&sm[cb][0]
                + (wr * 64 + m * 16 + lr) * 128 + ((kk * 64 + lg * 16) ^ kx));
#pragma unroll
      for (int n = 0; n < 4; n++)
        bfr[n] = *(const short8*)((const char*)&sm[cb][0] + 16384
                + (wc * 64 + n * 16 + lr) * 128 + ((kk * 64 + lg * 16) ^ kx));
#pragma unroll
      for (int m = 0; m < 4; m++)
#pragma unroll
        for (int n = 0; n < 4; n++)
          acc[m][n] = mfma16(a[m], bfr[n], acc[m][n]);
    }
    __syncthreads();
  }
#undef STAGEK

  if (n0 < 1024) {
    const float* bias = (n0 < 512) ? bq : bk;
    u16* dst = (n0 < 512) ? qb : kb;
    const float scl = (n0 < 512) ? QK_SCALE : 1.0f;
    const int nbase = n0 & 511;
#pragma unroll
    for (int n = 0; n < 4; n++) {
      int gn = nbase + wc * 64 + n * 16 + lr;
      float bia = bias[gn];
#pragma unroll
      for (int m = 0; m < 4; m++) {
        int gm0 = m0 + wr * 64 + m * 16 + lg * 4;
#pragma unroll
        for (int r = 0; r < 4; r++)
          dst[(size_t)(gm0 + r) * D_DIM + gn] = f2b((acc[m][n][r] + bia) * scl);
      }
    }
  } else {
    const int nbase = n0 - 1024;
    const int bIdx = m0 >> 11;
    const int s0 = m0 & 2047;
    __syncthreads();
#pragma unroll
    for (int h = 0; h < 2; ++h) {
      if (wc == h) {
#pragma unroll
        for (int n = 0; n < 4; n++) {
          int lrow = n * 16 + lr;
          float bia = bv[nbase + h * 64 + lrow];
#pragma unroll
          for (int m = 0; m < 4; m++) {
            int lcol = wr * 64 + m * 16 + lg * 4;
#pragma unroll
            for (int r = 0; r < 4; r++)
              sm[0][lrow * 136 + lcol + r] = f2b(acc[m][n][r] + bia);
          }
        }
      }
      __syncthreads();
      {
        int row = tid >> 2;
        int c0 = (tid & 3) * 32;
        u16* dstp = vt + (size_t)bIdx * D_DIM * S_LEN
                       + (size_t)(nbase + h * 64 + row) * S_LEN + s0 + c0;
        const u16* srcp = &sm[0][row * 136 + c0];
#pragma unroll
        for (int jj = 0; jj < 4; jj++)
          *(short8*)(dstp + jj * 8) = *(const short8*)(srcp + jj * 8);
      }
      __syncthreads();
    }
  }
}

// ---------------------------------------------------------------- S = exp(K.Q^T) GEMM
__launch_bounds__(256)
__global__ void s_gemm(const u16* __restrict__ qb,
                       const u16* __restrict__ kb,
                       u16* __restrict__ P,
                       float* __restrict__ pRS)
{
  __shared__ alignas(16) u16 sm[2][16384];
  const int tid = threadIdx.x;
  const int l = tid & 63, w = tid >> 6;
  const int lr = l & 15, lg = l >> 4;
  const int wr = w >> 1, wc = w & 1;
  const int kx = (lr & 7) << 4;
  const int csw = ((tid & 7) * 16) ^ (((tid >> 3) & 7) << 4);
  const int bid = blockIdx.x;
  const int xcd = bid & 7;
  const int b = xcd >> 1;
  const int j = (bid >> 3) * 2 + (xcd & 1);   // 0..135
  float g = sqrtf(8.f * (float)j + 1.f);
  int qt = (int)((g - 1.f) * 0.5f + 1e-4f);
  while ((qt + 1) * (qt + 2) / 2 <= j) ++qt;
  while (qt * (qt + 1) / 2 > j) --qt;
  const int kt = j - qt * (qt + 1) / 2;

  const u16* gA = kb + ((size_t)(b * S_LEN + kt * 128 + (tid >> 3))) * D_DIM + (csw >> 1);
  const u16* gB = qb + ((size_t)(b * S_LEN + qt * 128 + (tid >> 3))) * D_DIM + (csw >> 1);

#define STAGES(BUF, KT) { \
  char* la = (char*)&sm[BUF][0] + tid * 16; \
  char* lb = (char*)&sm[BUF][8192] + tid * 16; \
  const u16* ga = gA + (KT) * 64; \
  const u16* gb = gB + (KT) * 64; \
  _Pragma("unroll") for (int jj = 0; jj < 4; jj++) { \
    GLD16(ga + (size_t)jj * 32 * D_DIM, la + jj * 4096); \
    GLD16(gb + (size_t)jj * 32 * D_DIM, lb + jj * 4096); } }

  floatx4 acc[4][4];
#pragma unroll
  for (int m = 0; m < 4; m++)
#pragma unroll
    for (int n = 0; n < 4; n++) acc[m][n] = 0.0f;

  STAGES(0, 0)
  __syncthreads();
  for (int ks = 0; ks < 8; ++ks) {
    const int cb = ks & 1;
    if (ks < 7) STAGES(cb ^ 1, ks + 1)
#pragma unroll
    for (int kk = 0; kk < 2; ++kk) {
      short8 a[4], bfr[4];
#pragma unroll
      for (int m = 0; m < 4; m++)
        a[m] = *(const short8*)((const char*)&sm[cb][0]
                + (wr * 64 + m * 16 + lr) * 128 + ((kk * 64 + lg * 16) ^ kx));
#pragma unroll
      for (int n = 0; n < 4; n++)
        bfr[n] = *(const short8*)((const char*)&sm[cb][0] + 16384
                + (wc * 64 + n * 16 + lr) * 128 + ((kk * 64 + lg * 16) ^ kx));
#pragma unroll
      for (int m = 0; m < 4; m++)
#pragma unroll
        for (int n = 0; n < 4; n++)
          acc[m][n] = mfma16(a[m], bfr[n], acc[m][n]);
    }
    __syncthreads();
  }
#undef STAGES

  // epilogue: exp + mask, u64-packed P stores, rowsum partials
  const bool diag = (kt == qt);
  u16* Pb = P + (size_t)b * S_LEN * S_LEN;
#pragma unroll
  for (int n = 0; n < 4; ++n) {
    const int q = qt * 128 + wc * 64 + n * 16 + lr;
    float rs = 0.f;
#pragma unroll
    for (int m = 0; m < 4; ++m) {
      const int kb0 = kt * 128 + wr * 64 + m * 16 + lg * 4;
      u16 h[4];
#pragma unroll
      for (int r = 0; r < 4; ++r) {
        float e = __expf(acc[m][n][r]);
        if (diag && (kb0 + r > q)) e = 0.f;
        h[r] = f2b(e);
        rs += b2f(h[r]);
      }
      u64 pk = (u64)h[0] | ((u64)h[1] << 16) | ((u64)h[2] << 32) | ((u64)h[3] << 48);
      *(u64*)(Pb + (size_t)q * S_LEN + kb0) = pk;
    }
    rs += __shfl_xor(rs, 16);
    rs += __shfl_xor(rs, 32);
    if (lg == 0)
      pRS[(size_t)(b * S_LEN + q) * 32 + kt * 2 + wr] = rs;
  }
}

// ---------------------------------------------------------------- O = (P.V)/rsum (split-K for long qt)
// Grid 768. Per batch (2 XCD lanes): j in [0,128): CHUNK blocks for qt>=16 --
// kv split in 2 halves (<=16 steps), bf16 unnormalized partials; j in
// [128,192): DIRECT blocks qt<16 (<=16 steps), normalized f32 out. Both
// longest-first. Critical path 32 -> 16 steps.
__launch_bounds__(256)
__global__ void pv_gemm(const u16* __restrict__ P,
                       const float* __restrict__ pRS,
                       const u16* __restrict__ vt,
                       float* __restrict__ out,
                       u16* __restrict__ pOp)
{
  __shared__ alignas(16) u16 sm[2][12288];   // A 128x64 @0 | B 64x64 @byte 16384
  __shared__ float rinv[64];

  const int tid = threadIdx.x;
  const int l = tid & 63, w = tid >> 6;
  const int lr = l & 15, lg = l >> 4;
  const int wr = w >> 1, wc = w & 1;         // wave: 64d x 32q quadrant
  const int kx = (lr & 7) << 4;
  const int csw = ((tid & 7) * 16) ^ (((tid >> 3) & 7) << 4);
  const int bid = blockIdx.x;
  const int xcd = bid & 7;
  const int b = xcd >> 1, xl = xcd & 1;
  const int j = (bid >> 3) * 2 + xl;         // 0..191

  int qt, m, c0k, nsteps, slot;
  if (j < 128) {                             // chunk blocks (qt 16..31)
    const int cc = j & 1;
    const int mq = j >> 1;                   // 0..63
    m = mq & 3;
    qt = 31 - (mq >> 2);                     // 31..16 (longest first)
    const int nks = qt + 1;
    const int half = (nks + 1) >> 1;
    c0k = cc ? half : 0;
    nsteps = cc ? (nks - half) : half;
    slot = (((b * 16 + (qt - 16)) * 4 + m) << 1) | cc;
  } else {                                   // direct blocks (qt 0..15)
    const int jj = j - 128;                  // 0..63
    m = jj & 3;
    qt = 15 - (jj >> 2);                     // 15..0 (longest first)
    c0k = 0;
    nsteps = qt + 1;
    slot = -1;
  }
  const int m0 = m * 128;
  const int q0 = qt * 64;

  const u16* gA = vt + (size_t)b * D_DIM * S_LEN
                     + (size_t)(m0 + (tid >> 3)) * S_LEN + c0k * 64 + (csw >> 1);
  const u16* gB = P + (size_t)b * S_LEN * S_LEN
                    + (size_t)(q0 + (tid >> 3)) * S_LEN + c0k * 64 + (csw >> 1);

  // rsum prologue (direct path only; chunk partials are unnormalized)
  if (slot < 0) {
    const int qi = tid >> 2;                 // 0..63
    const int qrow = q0 + qi;
    const int ns = ((qrow >> 7) + 1) * 2;
    float s = 0.f;
    for (int ss = tid & 3; ss < ns; ss += 4)
      s += pRS[(size_t)(b * S_LEN + qrow) * 32 + ss];
    s += __shfl_xor(s, 1);
    s += __shfl_xor(s, 2);
    if ((tid & 3) == 0) rinv[qi] = 1.0f / s;
  }

#define STAGEPV(BUF, KS) { \
  char* la = (char*)&sm[BUF][0] + tid * 16; \
  char* lb = (char*)&sm[BUF][8192] + tid * 16; \
  const u16* ga = gA + (KS) * 64; \
  const u16* gb = gB + (KS) * 64; \
  _Pragma("unroll") for (int jj = 0; jj < 4; jj++) \
    GLD16(ga + (size_t)jj * 32 * S_LEN, la + jj * 4096); \
  _Pragma("unroll") for (int jj = 0; jj < 2; jj++) \
    GLD16(gb + (size_t)jj * 32 * S_LEN, lb + jj * 4096); }

  floatx4 acc[4][2];
#pragma unroll
  for (int mm = 0; mm < 4; mm++) { acc[mm][0] = 0.0f; acc[mm][1] = 0.0f; }

  STAGEPV(0, 0)
  __syncthreads();
  for (int ks = 0; ks < nsteps; ++ks) {
    const int cb = ks & 1;
    if (ks < nsteps - 1) STAGEPV(cb ^ 1, ks + 1)
#pragma unroll
    for (int kk = 0; kk < 2; ++kk) {
      short8 a[4], bfr[2];
#pragma unroll
      for (int mm = 0; mm < 4; mm++)
        a[mm] = *(const short8*)((const char*)&sm[cb][0]
                + (wr * 64 + mm * 16 + lr) * 128 + ((kk * 64 + lg * 16) ^ kx));
#pragma unroll
      for (int n = 0; n < 2; n++)
        bfr[n] = *(const short8*)((const char*)&sm[cb][0] + 16384
                + (wc * 32 + n * 16 + lr) * 128 + ((kk * 64 + lg * 16) ^ kx));
#pragma unroll
      for (int mm = 0; mm < 4; mm++)
#pragma unroll
        for (int n = 0; n < 2; n++)
          acc[mm][n] = mfma16(a[mm], bfr[n], acc[mm][n]);
    }
    __syncthreads();
  }
#undef STAGEPV

  if (slot >= 0) {
    // bf16 unnormalized partials [64q][128d], nontemporal
    u16* po = pOp + (size_t)slot * 8192;
#pragma unroll
    for (int n = 0; n < 2; ++n) {
      const int row = wc * 32 + n * 16 + lr;
#pragma unroll
      for (int mm = 0; mm < 4; ++mm) {
        const int dloc = wr * 64 + mm * 16 + lg * 4;
        u64 pk = (u64)f2b(acc[mm][n][0]) | ((u64)f2b(acc[mm][n][1]) << 16)
               | ((u64)f2b(acc[mm][n][2]) << 32) | ((u64)f2b(acc[mm][n][3]) << 48);
        __builtin_nontemporal_store(pk, (u64*)(po + row * 128 + dloc));
      }
    }
  } else {
    // normalize + float4 f32 out
#pragma unroll
    for (int n = 0; n < 2; ++n) {
      const int q = q0 + wc * 32 + n * 16 + lr;
      const float inv = rinv[wc * 32 + n * 16 + lr];
      float* op = out + (size_t)(b * S_LEN + q) * D_DIM + m0 + wr * 64 + lg * 4;
#pragma unroll
      for (int mm = 0; mm < 4; ++mm) {
        float4 v;
        v.x = acc[mm][n][0] * inv;
        v.y = acc[mm][n][1] * inv;
        v.z = acc[mm][n][2] * inv;
        v.w = acc[mm][n][3] * inv;
        *(float4*)(op + mm * 16) = v;
      }
    }
  }
}

// ---------------------------------------------------------------- sum chunk pairs, normalize
__launch_bounds__(256)
__global__ void pv_reduce(const u16* __restrict__ pOp,
                          const float* __restrict__ pRS,
                          float* __restrict__ out)
{
  const int id = blockIdx.x;           // ((b*16 + qq)*4 + m), qq = qt-16
  const int m = id & 3;
  const int qq = (id >> 2) & 15;
  const int b = id >> 6;
  const int qt = 16 + qq;
  const int q0 = qt * 64;
  const int m0 = m * 128;
  const int sbase = id * 2;

  const int row = threadIdx.x >> 2;            // 0..63
  const int col0 = (threadIdx.x & 3) * 32;     // 0..96
  const int qrow = q0 + row;

  const int ns = ((qrow >> 7) + 1) * 2;
  float s = 0.f;
  for (int ss = 0; ss < ns; ++ss)
    s += pRS[(size_t)(b * S_LEN + qrow) * 32 + ss];
  const float inv = 1.0f / s;

  const u16* s0p = pOp + (size_t)sbase * 8192 + row * 128 + col0;
  const u16* s1p = s0p + 8192;
  float* dst = out + (size_t)(b * S_LEN + qrow) * D_DIM + m0 + col0;
#pragma unroll
  for (int jj = 0; jj < 8; ++jj) {
    ushort4 a = ((const ushort4*)s0p)[jj];
    ushort4 c = ((const ushort4*)s1p)[jj];
    float4 v;
    v.x = (b2f(a.x) + b2f(c.x)) * inv;
    v.y = (b2f(a.y) + b2f(c.y)) * inv;
    v.z = (b2f(a.z) + b2f(c.z)) * inv;
    v.w = (b2f(a.w) + b2f(c.w)) * inv;
    *(float4*)(dst + jj * 4) = v;
  }
}

// ---------------------------------------------------------------- launch
extern "C" void kernel_launch(void* const* d_in, const int* in_sizes, int n_in,
                              void* d_out, int out_size, void* d_ws, size_t ws_size,
                              hipStream_t stream)
{
  const float* x  = (const float*)d_in[0];
  const float* Wq = (const float*)d_in[1];
  const float* bq = (const float*)d_in[2];
  const float* Wk = (const float*)d_in[3];
  const float* bk = (const float*)d_in[4];
  const float* Wv = (const float*)d_in[5];
  const float* bv = (const float*)d_in[6];
  float* out = (float*)d_out;

  u16* xw = (u16*)d_ws;
  u16* xb = xw;                              // [8192][512] bf16
  u16* wb = xb + (size_t)NROWS * D_DIM;      // [1536][512] bf16
  u16* qb = wb + (size_t)NQKV * D_DIM;       // [8192][512] bf16 (scaled)
  u16* kb = qb + (size_t)NROWS * D_DIM;      // [8192][512] bf16
  u16* vt = kb + (size_t)NROWS * D_DIM;      // [4][512][2048] bf16 (V^T)
  u16* P  = vt + (size_t)NROWS * D_DIM;      // [4][2048][2048] bf16 (exp scores)
  float* pRS = (float*)(P + (size_t)4 * S_LEN * S_LEN);  // [8192][32] f32 rowsum partials
  u16* pOp = (u16*)(pRS + (size_t)NROWS * 32);           // [512][64][128] bf16 pv partials

  hipLaunchKernelGGL(cvt_kernel, dim3(2048), dim3(256), 0, stream, x, Wq, Wk, Wv, xw);
  hipLaunchKernelGGL(qkv_gemm, dim3(768), dim3(256), 0, stream,
                     xb, wb, bq, bk, bv, qb, kb, vt);
  hipLaunchKernelGGL(s_gemm, dim3(544), dim3(256), 0, stream, qb, kb, P, pRS);
  hipLaunchKernelGGL(pv_gemm, dim3(768), dim3(256), 0, stream, P, pRS, vt, out, pOp);
  hipLaunchKernelGGL(pv_reduce, dim3(256), dim3(256), 0, stream, pOp, pRS, out);
}